// Round 11
// baseline (462.764 us; speedup 1.0000x reference)
//
#include <hip/hip_runtime.h>
#include <hip/hip_bf16.h>
#include <math.h>

// Problem constants
#define B_     16
#define DIM_   256
#define H_     32
#define W_     32
#define HW_    1024
#define C_     64
#define HEADS_ 8
#define DH_    64
#define INNER_ 512
#define TOK_   16384   // B_*HW_

typedef unsigned short ushort_t;
typedef __bf16 bf16x8 __attribute__((ext_vector_type(8)));
typedef float  f32x4  __attribute__((ext_vector_type(4)));

// ---- fp32 arena offsets for all non-x inputs (element offsets) ----
#define AOFF_N1W     0
#define AOFF_N1B     256
#define AOFF_ALNW    512
#define AOFF_ALNB    576
#define AOFF_WQKV    640
#define AOFF_WOUT    98944
#define AOFF_PXY     131712
#define AOFF_CXYDW   135808
#define AOFF_CXYDWB  136384
#define AOFF_CXYPW   136448
#define AOFF_CXYPWB  140544
#define AOFF_CAF1    140608
#define AOFF_CAF2    140864
#define AOFF_SAW     141120
#define AOFF_PZX     141218
#define AOFF_CZXDW   141730
#define AOFF_CZXDWB  141922
#define AOFF_CZXPW   141986
#define AOFF_CZXPWB  146082
#define AOFF_SEF1    146146
#define AOFF_SEF2    146402
#define AOFF_PZY     146658
#define AOFF_CZYDW   147170
#define AOFF_CZYDWB  147362
#define AOFF_CZYPW   147426
#define AOFF_CZYPWB  151522
#define AOFF_DWPW    151586
#define AOFF_DWPWB   155682
#define AOFF_DWDW    155746
#define AOFF_DWDWB   156322
#define AOFF_N2W     156386
#define AOFF_N2B     156642
#define AOFF_LDWDW   156898
#define AOFF_LDWDWB  159202
#define AOFF_LDWPW   159458
#define AOFF_LDWPWB  224994
#define ATOTAL       225250

__device__ __forceinline__ float us2f(ushort_t u) {
  union { unsigned int i; float f; } v; v.i = ((unsigned int)u) << 16; return v.f;
}
__device__ __forceinline__ ushort_t f2us(float f) {
  union { float f; unsigned int i; } v; v.f = f;
  unsigned int x = v.i;
  return (ushort_t)((x + 0x7fffu + ((x >> 16) & 1u)) >> 16);
}
__device__ __forceinline__ float ldx(const void* p, size_t i, bool f32) {
  return f32 ? ((const float*)p)[i] : us2f(((const ushort_t*)p)[i]);
}
__device__ __forceinline__ float gelu_f(float x) {
  return 0.5f * x * (1.0f + erff(x * 0.70710678118654752f));
}
__device__ __forceinline__ float sigmoid_f(float x) {
  return 1.0f / (1.0f + __expf(-x));
}

// ---------- dtype probe ----------
__global__ void k_probe(const ushort_t* __restrict__ x, int* __restrict__ dtf) {
  __shared__ int cnt;
  if (threadIdx.x == 0) cnt = 0;
  __syncthreads();
  int c = 0;
  for (int i = threadIdx.x; i < 2048; i += 256) {
    int e = (x[i] >> 7) & 0xFF;
    if (e >= 160) ++c;
  }
  atomicAdd(&cnt, c);
  __syncthreads();
  if (threadIdx.x == 0) dtf[0] = (cnt > 16) ? 1 : 0;
}

__global__ void k_diag(void* __restrict__ out, const int* __restrict__ dtf, float val) {
  bool f32 = dtf[0] != 0;
  int i = blockIdx.x * 256 + threadIdx.x;
  if (i < B_ * DIM_ * HW_) {
    if (f32) ((float*)out)[i] = val; else ((ushort_t*)out)[i] = f2us(val);
  }
}

// ---------- convert all 36 non-x inputs into one fp32 arena ----------
__global__ void k_cvt_all(const void* p0,const void* p1,const void* p2,const void* p3,const void* p4,
                          const void* p5,const void* p6,const void* p7,const void* p8,const void* p9,
                          const void* p10,const void* p11,const void* p12,const void* p13,const void* p14,
                          const void* p15,const void* p16,const void* p17,const void* p18,const void* p19,
                          const void* p20,const void* p21,const void* p22,const void* p23,const void* p24,
                          const void* p25,const void* p26,const void* p27,const void* p28,const void* p29,
                          const void* p30,const void* p31,const void* p32,const void* p33,const void* p34,
                          const void* p35, const int* __restrict__ dtf, float* __restrict__ arena) {
  const void* ps[36] = {p0,p1,p2,p3,p4,p5,p6,p7,p8,p9,p10,p11,p12,p13,p14,p15,p16,p17,
                        p18,p19,p20,p21,p22,p23,p24,p25,p26,p27,p28,p29,p30,p31,p32,p33,p34,p35};
  const int offs[37] = {AOFF_N1W,AOFF_N1B,AOFF_ALNW,AOFF_ALNB,AOFF_WQKV,AOFF_WOUT,AOFF_PXY,
    AOFF_CXYDW,AOFF_CXYDWB,AOFF_CXYPW,AOFF_CXYPWB,AOFF_CAF1,AOFF_CAF2,AOFF_SAW,AOFF_PZX,
    AOFF_CZXDW,AOFF_CZXDWB,AOFF_CZXPW,AOFF_CZXPWB,AOFF_SEF1,AOFF_SEF2,AOFF_PZY,AOFF_CZYDW,
    AOFF_CZYDWB,AOFF_CZYPW,AOFF_CZYPWB,AOFF_DWPW,AOFF_DWPWB,AOFF_DWDW,AOFF_DWDWB,AOFF_N2W,
    AOFF_N2B,AOFF_LDWDW,AOFF_LDWDWB,AOFF_LDWPW,AOFF_LDWPWB,ATOTAL};
  bool f32 = dtf[0] != 0;
  int gid = blockIdx.x * 256 + threadIdx.x;
  if (gid >= ATOTAL) return;
  int t = 0;
  while (offs[t + 1] <= gid) ++t;
  int loc = gid - offs[t];
  arena[gid] = f32 ? ((const float*)ps[t])[loc] : us2f(((const ushort_t*)ps[t])[loc]);
}

// ---------- bf16 weight prep ----------
__global__ void k_wprep(const float* __restrict__ arena, ushort_t* __restrict__ wqkvT,
                        ushort_t* __restrict__ woutT, ushort_t* __restrict__ wpwB,
                        ushort_t* __restrict__ wdwpwB) {
  int gid = blockIdx.x * 256 + threadIdx.x;
  if (gid < 98304) {                       // wqkvT[j*64+c] = wqkv[c*1536+j]
    int j = gid >> 6, c = gid & 63;
    wqkvT[gid] = f2us(arena[AOFF_WQKV + c * 1536 + j]);
  } else if (gid < 131072) {               // woutT[c*512+j] = wout[j*64+c]
    int g = gid - 98304;
    int c = g >> 9, j = g & 511;
    woutT[g] = f2us(arena[AOFF_WOUT + j * 64 + c]);
  } else if (gid < 196608) {               // wpwB[d*256+c] = ldw_pw[d][c]
    int g = gid - 131072;
    wpwB[g] = f2us(arena[AOFF_LDWPW + g]);
  } else if (gid < 200704) {               // wdwpwB[cout*64+cin] = dw_pw[cout][cin]
    int g = gid - 196608;
    wdwpwB[g] = f2us(arena[AOFF_DWPW + g]);
  }
}

// ---------- LN1 stats (4-way channel split, 256 blocks) ----------
__global__ __launch_bounds__(256) void k_ln1stats(const void* __restrict__ x, const int* __restrict__ dtf,
                                                  float* __restrict__ m1, float* __restrict__ r1) {
  __shared__ float ps[4][64], ps2[4][64];
  bool xf = dtf[0] != 0;
  int t = threadIdx.x;
  int pi = t & 63, p = t >> 6;
  int pix = blockIdx.x * 64 + pi;
  int bb = pix >> 10, hw = pix & 1023;
  size_t base = (size_t)bb * (DIM_ * HW_) + hw;
  float s = 0.f, s2 = 0.f;
  for (int c = 0; c < 64; ++c) {
    float v = ldx(x, base + (size_t)(p * 64 + c) * HW_, xf);
    s += v; s2 += v * v;
  }
  ps[p][pi] = s; ps2[p][pi] = s2;
  __syncthreads();
  if (t < 64) {
    float S = ps[0][t] + ps[1][t] + ps[2][t] + ps[3][t];
    float S2 = ps2[0][t] + ps2[1][t] + ps2[2][t] + ps2[3][t];
    float mean = S * (1.0f / DIM_);
    float var = fmaxf(S2 * (1.0f / DIM_) - mean * mean, 0.f);
    int px = blockIdx.x * 64 + t;
    m1[px] = mean;
    r1[px] = rsqrtf(var + 1e-6f);
  }
}

// ---------- fused LN1 + token-LN -> x1ln bf16; also LN1-only xn4 (ch 192..255) ----------
__global__ __launch_bounds__(256) void k_ln_tok(const void* __restrict__ x, const int* __restrict__ dtf,
                                                const float* __restrict__ m1, const float* __restrict__ r1,
                                                const float* __restrict__ arena, ushort_t* __restrict__ x1ln,
                                                ushort_t* __restrict__ xn4) {
  __shared__ float ls[64 * 65];
  __shared__ float pm[4][64], pv[4][64];
  __shared__ float mt[64], rt[64];
  bool xf = dtf[0] != 0;
  int t = threadIdx.x;
  int bb = blockIdx.x >> 4, hw0 = (blockIdx.x & 15) * 64;
  // phase 1: ch 0..63, LN1 + token-LN -> x1ln
  #pragma unroll
  for (int i = 0; i < 16; ++i) {
    int ch = i * 4 + (t >> 6);
    int tk = t & 63;
    int tokg = bb * HW_ + hw0 + tk;
    float v = ldx(x, ((size_t)bb * DIM_ + ch) * HW_ + hw0 + tk, xf);
    ls[ch * 65 + tk] = (v - m1[tokg]) * r1[tokg] * arena[AOFF_N1W + ch] + arena[AOFF_N1B + ch];
  }
  __syncthreads();
  {
    int p = t >> 6, tk = t & 63;
    float s = 0.f, s2 = 0.f;
    #pragma unroll
    for (int c = 0; c < 16; ++c) {
      float v = ls[(p * 16 + c) * 65 + tk];
      s += v; s2 += v * v;
    }
    pm[p][tk] = s; pv[p][tk] = s2;
  }
  __syncthreads();
  if (t < 64) {
    float S = pm[0][t] + pm[1][t] + pm[2][t] + pm[3][t];
    float S2 = pv[0][t] + pv[1][t] + pv[2][t] + pv[3][t];
    float m = S * (1.0f / C_);
    float var = fmaxf(S2 * (1.0f / C_) - m * m, 0.f);
    mt[t] = m;
    rt[t] = rsqrtf(var + 1e-5f);
  }
  __syncthreads();
  {
    unsigned int* dst = (unsigned int*)x1ln;
    #pragma unroll
    for (int i = 0; i < 8; ++i) {
      int idx = i * 256 + t;
      int tok = idx >> 5, cp = idx & 31, c = cp * 2;
      float m = mt[tok], r = rt[tok];
      float v0 = (ls[c * 65 + tok] - m) * r * arena[AOFF_ALNW + c] + arena[AOFF_ALNB + c];
      float v1 = (ls[(c + 1) * 65 + tok] - m) * r * arena[AOFF_ALNW + c + 1] + arena[AOFF_ALNB + c + 1];
      int tokg = bb * HW_ + hw0 + tok;
      dst[(tokg * 64 + c) >> 1] = (unsigned int)f2us(v0) | ((unsigned int)f2us(v1) << 16);
    }
  }
  // phase 2: ch 192..255, LN1 only -> xn4 (for branch-4 MFMA GEMM)
  __syncthreads();
  #pragma unroll
  for (int i = 0; i < 16; ++i) {
    int ch = i * 4 + (t >> 6);
    int tk = t & 63;
    int tokg = bb * HW_ + hw0 + tk;
    float v = ldx(x, ((size_t)bb * DIM_ + 192 + ch) * HW_ + hw0 + tk, xf);
    ls[ch * 65 + tk] = (v - m1[tokg]) * r1[tokg] * arena[AOFF_N1W + 192 + ch] + arena[AOFF_N1B + 192 + ch];
  }
  __syncthreads();
  {
    unsigned int* dst = (unsigned int*)xn4;
    #pragma unroll
    for (int i = 0; i < 8; ++i) {
      int idx = i * 256 + t;
      int tok = idx >> 5, cp = idx & 31, c = cp * 2;
      float v0 = ls[c * 65 + tok];
      float v1 = ls[(c + 1) * 65 + tok];
      int tokg = bb * HW_ + hw0 + tok;
      dst[(tokg * 64 + c) >> 1] = (unsigned int)f2us(v0) | ((unsigned int)f2us(v1) << 16);
    }
  }
}

// ---------- QKV projection via MFMA: [tok,64] @ [64,1536] ----------
__global__ __launch_bounds__(256) void k_qkv_mfma(const ushort_t* __restrict__ x1ln,
                                                  const ushort_t* __restrict__ wqkvT,
                                                  ushort_t* __restrict__ q, ushort_t* __restrict__ k_,
                                                  ushort_t* __restrict__ v_, int tok_base) {
  int jc = blockIdx.x % 6;
  int mt = blockIdx.x / 6;
  int w = threadIdx.x >> 6, lane = threadIdx.x & 63;
  int m = lane & 15, quad = lane >> 4;
  int tok0 = mt * 64;                      // split-local
  bf16x8 a[4][2];
  #pragma unroll
  for (int s = 0; s < 4; ++s)
    #pragma unroll
    for (int kc = 0; kc < 2; ++kc)
      a[s][kc] = *(const bf16x8*)(x1ln + (size_t)(tok_base + tok0 + s*16 + m) * 64 + kc*32 + quad*8);
  bf16x8 bfr[4][2];
  #pragma unroll
  for (int nb = 0; nb < 4; ++nb)
    #pragma unroll
    for (int kc = 0; kc < 2; ++kc)
      bfr[nb][kc] = *(const bf16x8*)(wqkvT + (size_t)(jc*256 + w*64 + nb*16 + m) * 64 + kc*32 + quad*8);
  f32x4 cacc[4][4];
  #pragma unroll
  for (int s = 0; s < 4; ++s)
    #pragma unroll
    for (int nb = 0; nb < 4; ++nb) cacc[s][nb] = (f32x4){0.f, 0.f, 0.f, 0.f};
  #pragma unroll
  for (int kc = 0; kc < 2; ++kc)
    #pragma unroll
    for (int s = 0; s < 4; ++s)
      #pragma unroll
      for (int nb = 0; nb < 4; ++nb)
        cacc[s][nb] = __builtin_amdgcn_mfma_f32_16x16x32_bf16(a[s][kc], bfr[nb][kc], cacc[s][nb], 0, 0, 0);
  #pragma unroll
  for (int nb = 0; nb < 4; ++nb) {
    int j = jc*256 + w*64 + nb*16 + m;      // n = lane&15
    int which = j >> 9, jj = j & 511;
    int h = jj >> 6, d = jj & 63;
    ushort_t* dst = (which == 0) ? q : ((which == 1) ? k_ : v_);
    float sc = (which == 0) ? 0.125f : 1.0f;
    #pragma unroll
    for (int s = 0; s < 4; ++s)
      #pragma unroll
      for (int r = 0; r < 4; ++r) {
        int tl = tok0 + s*16 + quad*4 + r;  // split-local token (row)
        int bl = tl >> 10, n = tl & 1023;
        dst[(((size_t)bl * HEADS_ + h) * 1024 + n) * 64 + d] = f2us(cacc[s][nb][r] * sc);
      }
  }
}

// ---------- MFMA flash attention (256 q-rows/block, bf16 ao out) — round-9 body ----------
#define KSTR 72
__global__ __launch_bounds__(256) void k_flash_mfma(const ushort_t* __restrict__ q,
                                                    const ushort_t* __restrict__ k_,
                                                    const ushort_t* __restrict__ v_,
                                                    ushort_t* __restrict__ ao) {
  __shared__ ushort_t Kl[64 * KSTR];    // [key][d]
  __shared__ ushort_t Vt[64 * KSTR];    // [d][key]
  __shared__ ushort_t Pl[256 * KSTR];   // [qlocal(256)][key]
  int bh = blockIdx.x >> 2;
  int qt = blockIdx.x & 3;
  int w = threadIdx.x >> 6, lane = threadIdx.x & 63;
  int m = lane & 15, quad = lane >> 4;
  const size_t bh_off = (size_t)bh * 1024 * 64;

  bf16x8 aq[4][2];
  #pragma unroll
  for (int s = 0; s < 4; ++s)
    #pragma unroll
    for (int kc = 0; kc < 2; ++kc)
      aq[s][kc] = *(const bf16x8*)(q + bh_off + (size_t)(qt*256 + w*64 + s*16 + m) * 64 + kc*32 + quad*8);

  f32x4 oacc[4][4];
  float lacc[4][4];
  #pragma unroll
  for (int s = 0; s < 4; ++s)
    #pragma unroll
    for (int i = 0; i < 4; ++i) {
      oacc[s][i] = (f32x4){0.f, 0.f, 0.f, 0.f};
      lacc[s][i] = 0.f;
    }

  int kkey = threadIdx.x & 63;
  int kd0  = (threadIdx.x >> 6) * 16;
  int vkey = (threadIdx.x & 31) * 2;
  int vd0  = (threadIdx.x >> 5) * 8;

  for (int kt = 0; kt < 16; ++kt) {
    __syncthreads();
    {
      const uint4* src = (const uint4*)(k_ + bh_off + (size_t)(kt*64 + kkey)*64 + kd0);
      uint4 u0 = src[0], u1 = src[1];
      uint4* dst = (uint4*)&Kl[kkey * KSTR + kd0];
      dst[0] = u0; dst[1] = u1;
    }
    {
      const ushort4* s0 = (const ushort4*)(v_ + bh_off + (size_t)(kt*64 + vkey)*64 + vd0);
      const ushort4* s1 = (const ushort4*)(v_ + bh_off + (size_t)(kt*64 + vkey + 1)*64 + vd0);
      ushort4 x0 = s0[0], x1 = s0[1];
      ushort4 y0 = s1[0], y1 = s1[1];
      unsigned int* base = (unsigned int*)&Vt[0];
      int col = vkey >> 1;
      base[(vd0+0)*(KSTR/2) + col] = (unsigned int)x0.x | ((unsigned int)y0.x << 16);
      base[(vd0+1)*(KSTR/2) + col] = (unsigned int)x0.y | ((unsigned int)y0.y << 16);
      base[(vd0+2)*(KSTR/2) + col] = (unsigned int)x0.z | ((unsigned int)y0.z << 16);
      base[(vd0+3)*(KSTR/2) + col] = (unsigned int)x0.w | ((unsigned int)y0.w << 16);
      base[(vd0+4)*(KSTR/2) + col] = (unsigned int)x1.x | ((unsigned int)y1.x << 16);
      base[(vd0+5)*(KSTR/2) + col] = (unsigned int)x1.y | ((unsigned int)y1.y << 16);
      base[(vd0+6)*(KSTR/2) + col] = (unsigned int)x1.z | ((unsigned int)y1.z << 16);
      base[(vd0+7)*(KSTR/2) + col] = (unsigned int)x1.w | ((unsigned int)y1.w << 16);
    }
    __syncthreads();

    f32x4 sacc[4][4];
    #pragma unroll
    for (int s = 0; s < 4; ++s)
      #pragma unroll
      for (int kb = 0; kb < 4; ++kb) sacc[s][kb] = (f32x4){0.f, 0.f, 0.f, 0.f};
    #pragma unroll
    for (int kb = 0; kb < 4; ++kb) {
      bf16x8 bk0 = *(const bf16x8*)&Kl[(kb*16 + m) * KSTR + quad*8];
      bf16x8 bk1 = *(const bf16x8*)&Kl[(kb*16 + m) * KSTR + 32 + quad*8];
      #pragma unroll
      for (int s = 0; s < 4; ++s) {
        sacc[s][kb] = __builtin_amdgcn_mfma_f32_16x16x32_bf16(aq[s][0], bk0, sacc[s][kb], 0, 0, 0);
        sacc[s][kb] = __builtin_amdgcn_mfma_f32_16x16x32_bf16(aq[s][1], bk1, sacc[s][kb], 0, 0, 0);
      }
    }

    #pragma unroll
    for (int s = 0; s < 4; ++s) {
      float rs0 = 0.f, rs1 = 0.f, rs2 = 0.f, rs3 = 0.f;
      #pragma unroll
      for (int kb = 0; kb < 4; ++kb) {
        float p0 = __expf(fminf(sacc[s][kb][0], 30.f));
        float p1 = __expf(fminf(sacc[s][kb][1], 30.f));
        float p2 = __expf(fminf(sacc[s][kb][2], 30.f));
        float p3 = __expf(fminf(sacc[s][kb][3], 30.f));
        rs0 += p0; rs1 += p1; rs2 += p2; rs3 += p3;
        int rbase = (w*64 + s*16 + quad*4) * KSTR + kb*16 + m;
        Pl[rbase + 0*KSTR] = f2us(p0);
        Pl[rbase + 1*KSTR] = f2us(p1);
        Pl[rbase + 2*KSTR] = f2us(p2);
        Pl[rbase + 3*KSTR] = f2us(p3);
      }
      #pragma unroll
      for (int mask = 1; mask <= 8; mask <<= 1) {
        rs0 += __shfl_xor(rs0, mask, 64);
        rs1 += __shfl_xor(rs1, mask, 64);
        rs2 += __shfl_xor(rs2, mask, 64);
        rs3 += __shfl_xor(rs3, mask, 64);
      }
      lacc[s][0] += rs0; lacc[s][1] += rs1; lacc[s][2] += rs2; lacc[s][3] += rs3;
    }

    bf16x8 ap[4][2];
    #pragma unroll
    for (int s = 0; s < 4; ++s)
      #pragma unroll
      for (int kc = 0; kc < 2; ++kc)
        ap[s][kc] = *(const bf16x8*)&Pl[(w*64 + s*16 + m) * KSTR + kc*32 + quad*8];
    #pragma unroll
    for (int db = 0; db < 4; ++db) {
      bf16x8 bv0 = *(const bf16x8*)&Vt[(db*16 + m) * KSTR + quad*8];
      bf16x8 bv1 = *(const bf16x8*)&Vt[(db*16 + m) * KSTR + 32 + quad*8];
      #pragma unroll
      for (int s = 0; s < 4; ++s) {
        oacc[s][db] = __builtin_amdgcn_mfma_f32_16x16x32_bf16(ap[s][0], bv0, oacc[s][db], 0, 0, 0);
        oacc[s][db] = __builtin_amdgcn_mfma_f32_16x16x32_bf16(ap[s][1], bv1, oacc[s][db], 0, 0, 0);
      }
    }
  }

  // epilogue: normalize, write ao bf16 [tok][h*64+d] (split-local)
  int bl = bh >> 3, h = bh & 7;
  #pragma unroll
  for (int s = 0; s < 4; ++s) {
    #pragma unroll
    for (int r = 0; r < 4; ++r) {
      float inv = 1.0f / lacc[s][r];
      int qrow = qt*256 + w*64 + s*16 + quad*4 + r;
      ushort_t* op = ao + ((size_t)(bl*1024 + qrow)) * INNER_ + h*64 + m;
      #pragma unroll
      for (int db = 0; db < 4; ++db) op[db*16] = f2us(oacc[s][db][r] * inv);
    }
  }
}

// ---------- attention out-proj via MFMA ----------
__global__ __launch_bounds__(256) void k_outproj_mfma(const ushort_t* __restrict__ ao,
                                                      const ushort_t* __restrict__ woutT,
                                                      const float* __restrict__ g1,
                                                      ushort_t* __restrict__ cat, int tok_base) {
  int w = threadIdx.x >> 6, lane = threadIdx.x & 63;
  int m = lane & 15, quad = lane >> 4;
  int tok0 = blockIdx.x * 64 + w * 16;     // split-local
  f32x4 cacc[4];
  #pragma unroll
  for (int nb = 0; nb < 4; ++nb) cacc[nb] = (f32x4){0.f, 0.f, 0.f, 0.f};
  for (int kc = 0; kc < 16; ++kc) {
    bf16x8 a = *(const bf16x8*)(ao + (size_t)(tok0 + m) * INNER_ + kc*32 + quad*8);
    #pragma unroll
    for (int nb = 0; nb < 4; ++nb) {
      bf16x8 b = *(const bf16x8*)(woutT + (size_t)(nb*16 + m) * INNER_ + kc*32 + quad*8);
      cacc[nb] = __builtin_amdgcn_mfma_f32_16x16x32_bf16(a, b, cacc[nb], 0, 0, 0);
    }
  }
  #pragma unroll
  for (int nb = 0; nb < 4; ++nb) {
    int c = nb*16 + m;                     // n = lane&15
    #pragma unroll
    for (int r = 0; r < 4; ++r) {
      int tokg = tok_base + tok0 + quad*4 + r;
      int bb = tokg >> 10, hw = tokg & 1023;
      cat[((size_t)bb * DIM_ + c) * HW_ + hw] = f2us(cacc[nb][r] * g1[c * HW_ + hw]);
    }
  }
}

// ---------- gate xy fully fused: grid 16 (64 hw each); dw+resize -> LDS -> pw ----------
__global__ __launch_bounds__(256) void k_gate_xy(const float* __restrict__ arena,
                                                 float* __restrict__ g1) {
  __shared__ float ts[C_ * 64];   // [c][hw_local], 16 KB
  int t = threadIdx.x;
  int hw0 = blockIdx.x * 64;
  const float* w = arena + AOFF_CXYDW;
  const float* b = arena + AOFF_CXYDWB;
  #pragma unroll
  for (int i = 0; i < 16; ++i) {
    int e = i * 256 + t;
    int c = e >> 6, hwl = e & 63;
    int hw = hw0 + hwl;
    int yy = hw >> 5, xx = hw & 31;
    const float* pc = arena + AOFF_PXY + c * 64;
    float acc = b[c];
    #pragma unroll
    for (int ky = 0; ky < 3; ++ky) {
      int ny = yy + ky - 1; if (ny < 0 || ny > 31) continue;
      float sy = ny * (7.0f / 31.0f); int y0 = (int)floorf(sy); y0 = y0 > 6 ? 6 : y0; float fy = sy - y0;
      #pragma unroll
      for (int kx = 0; kx < 3; ++kx) {
        int nx = xx + kx - 1; if (nx < 0 || nx > 31) continue;
        float sx = nx * (7.0f / 31.0f); int x0 = (int)floorf(sx); x0 = x0 > 6 ? 6 : x0; float fx = sx - x0;
        float a  = pc[y0*8+x0] * (1.f-fy) + pc[(y0+1)*8+x0] * fy;
        float b2 = pc[y0*8+x0+1] * (1.f-fy) + pc[(y0+1)*8+x0+1] * fy;
        acc += w[c*9 + ky*3 + kx] * (a * (1.f - fx) + b2 * fx);
      }
    }
    ts[c * 64 + hwl] = gelu_f(acc);
  }
  __syncthreads();
  const float* wp = arena + AOFF_CXYPW;
  const float* bp = arena + AOFF_CXYPWB;
  #pragma unroll
  for (int i = 0; i < 16; ++i) {
    int e = i * 256 + t;
    int d = e >> 6, hwl = e & 63;
    float acc = bp[d];
    for (int c = 0; c < C_; ++c) acc += wp[d*C_ + c] * ts[c*64 + hwl];
    g1[d * HW_ + hw0 + hwl] = acc;
  }
}

// ---------- 1d gates, fully fused: grid 2 (block 0: zx -> g2, block 1: zy -> g3) ----------
__global__ __launch_bounds__(256) void k_gate_full(const float* __restrict__ arena,
                                                   float* __restrict__ g2, float* __restrict__ g3) {
  __shared__ float ts[C_ * 32];
  int gi = blockIdx.x;
  int po  = gi ? AOFF_PZY   : AOFF_PZX;
  int wo  = gi ? AOFF_CZYDW : AOFF_CZXDW;
  int bo  = gi ? AOFF_CZYDWB: AOFF_CZXDWB;
  int pwo = gi ? AOFF_CZYPW : AOFF_CZXPW;
  int pbo = gi ? AOFF_CZYPWB: AOFF_CZXPWB;
  float* g = gi ? g3 : g2;
  const float* p   = arena + po;
  const float* dww = arena + wo;
  const float* dwb = arena + bo;
  for (int idx = threadIdx.x; idx < C_ * 32; idx += 256) {
    int c = idx >> 5, i = idx & 31;
    float acc = dwb[c];
    #pragma unroll
    for (int kk = 0; kk < 3; ++kk) {
      int ii = i + kk - 1;
      if (ii < 0 || ii > 31) continue;
      float s = ii * (7.0f / 31.0f); int x0 = (int)floorf(s); x0 = x0 > 6 ? 6 : x0; float f = s - x0;
      float val = p[c*8 + x0] * (1.f - f) + p[c*8 + x0 + 1] * f;
      acc += dww[c*3 + kk] * val;
    }
    ts[idx] = gelu_f(acc);
  }
  __syncthreads();
  const float* w = arena + pwo;
  const float* b = arena + pbo;
  for (int idx = threadIdx.x; idx < C_ * 32; idx += 256) {
    int d = idx >> 5, i = idx & 31;
    float acc = b[d];
    for (int c = 0; c < C_; ++c) acc += w[d*C_ + c] * ts[c*32 + i];
    g[idx] = acc;
  }
}

// ---------- pooling, both branches in one launch (grid 2048) ----------
__global__ __launch_bounds__(256) void k_pool2(const void* __restrict__ x, const int* __restrict__ dtf,
                                               const float* __restrict__ m1, const float* __restrict__ r1,
                                               const float* __restrict__ arena,
                                               float* __restrict__ camean, float* __restrict__ camax,
                                               float* __restrict__ sem, float* __restrict__ semx) {
  __shared__ float sm[256], sx[256];
  bool xf = dtf[0] != 0;
  int which = blockIdx.x >> 10;
  int blk = blockIdx.x & 1023;
  int coff = which ? 128 : 64;
  float* om = which ? sem  : camean;
  float* ox = which ? semx : camax;
  int bb = blk >> 6, c = blk & 63;
  const size_t xbase = ((size_t)bb * DIM_ + coff + c) * HW_;
  const float* mb = m1 + bb * HW_;
  const float* rb = r1 + bb * HW_;
  float wc = arena[AOFF_N1W + coff + c], bc = arena[AOFF_N1B + coff + c];
  int tid = threadIdx.x;
  float s = 0.f, mx = -1e30f;
  for (int i = tid; i < HW_; i += 256) {
    float v = (ldx(x, xbase + i, xf) - mb[i]) * rb[i] * wc + bc;
    s += v; mx = fmaxf(mx, v);
  }
  sm[tid] = s; sx[tid] = mx; __syncthreads();
  for (int st = 128; st > 0; st >>= 1) {
    if (tid < st) { sm[tid] += sm[tid+st]; sx[tid] = fmaxf(sx[tid], sx[tid+st]); }
    __syncthreads();
  }
  if (tid == 0) { om[blk] = sm[0] * (1.0f / HW_); ox[blk] = sx[0]; }
}

// ---------- channel MLPs fused: grid 32 (0..15 = CBAM ca, 16..31 = SE) ----------
__global__ void k_chmlp(const float* __restrict__ camean, const float* __restrict__ camax,
                        const float* __restrict__ sem, const float* __restrict__ arena,
                        float* __restrict__ ca, float* __restrict__ se) {
  __shared__ float hid[8];
  int which = blockIdx.x >> 4;
  int bb = blockIdx.x & 15, tid = threadIdx.x;
  if (!which) {
    const float* fc1 = arena + AOFF_CAF1;
    const float* fc2 = arena + AOFF_CAF2;
    if (tid < 8) {
      int half = tid >> 2, r = tid & 3;
      const float* src = half ? camax : camean;
      float s = 0.f;
      for (int c = 0; c < C_; ++c) s += src[bb*C_ + c] * fc1[r*C_ + c];
      hid[tid] = fmaxf(s, 0.f);
    }
    __syncthreads();
    float s = 0.f;
    #pragma unroll
    for (int r = 0; r < 4; ++r) s += (hid[r] + hid[4+r]) * fc2[tid*4 + r];
    ca[bb*C_ + tid] = sigmoid_f(s);
  } else {
    const float* fc1 = arena + AOFF_SEF1;
    const float* fc2 = arena + AOFF_SEF2;
    if (tid < 4) {
      float s = 0.f;
      for (int c = 0; c < C_; ++c) s += sem[bb*C_ + c] * fc1[tid*C_ + c];
      hid[tid] = fmaxf(s, 0.f);
    }
    __syncthreads();
    float s = 0.f;
    #pragma unroll
    for (int r = 0; r < 4; ++r) s += hid[r] * fc2[tid*4 + r];
    se[bb*C_ + tid] = sigmoid_f(s);
  }
}

// ---------- spatial maps (4-way channel split, 256 blocks) ----------
__global__ __launch_bounds__(256) void k_spmaps(const void* __restrict__ x, const int* __restrict__ dtf,
                                                const float* __restrict__ m1, const float* __restrict__ r1,
                                                const float* __restrict__ arena, const float* __restrict__ ca,
                                                float* __restrict__ spm, float* __restrict__ spx) {
  __shared__ float ps[4][64], px[4][64];
  bool xf = dtf[0] != 0;
  int t = threadIdx.x;
  int pi = t & 63, p = t >> 6;
  int pix = blockIdx.x * 64 + pi;
  int bb = pix >> 10, hw = pix & 1023;
  float m = m1[pix], r = r1[pix];
  float s = 0.f, mx = -1e30f;
  for (int c = 0; c < 16; ++c) {
    int ch = p * 16 + c;
    float v = (ldx(x, ((size_t)bb * DIM_ + 64 + ch) * HW_ + hw, xf) - m) * r * arena[AOFF_N1W + 64 + ch] + arena[AOFF_N1B + 64 + ch];
    v *= ca[bb*C_ + ch];
    s += v; mx = fmaxf(mx, v);
  }
  ps[p][pi] = s; px[p][pi] = mx;
  __syncthreads();
  if (t < 64) {
    float S = ps[0][t] + ps[1][t] + ps[2][t] + ps[3][t];
    float M = fmaxf(fmaxf(px[0][t], px[1][t]), fmaxf(px[2][t], px[3][t]));
    int pxi = blockIdx.x * 64 + t;
    spm[pxi] = S * (1.0f / C_);
    spx[pxi] = M;
  }
}

__global__ void k_saconv(const float* __restrict__ spm, const float* __restrict__ spx,
                         const float* __restrict__ arena, float* __restrict__ samask) {
  const float* w = arena + AOFF_SAW;
  int idx = blockIdx.x * 256 + threadIdx.x;
  int bb = idx >> 10, hw = idx & 1023, yy = hw >> 5, xx = hw & 31;
  float acc = 0.f;
  for (int ky = 0; ky < 7; ++ky) {
    int ny = yy + ky - 3; if (ny < 0 || ny > 31) continue;
    for (int kx = 0; kx < 7; ++kx) {
      int nx = xx + kx - 3; if (nx < 0 || nx > 31) continue;
      int off = bb*HW_ + ny*32 + nx;
      acc += spm[off] * w[ky*7 + kx] + spx[off] * w[49 + ky*7 + kx];
    }
  }
  samask[idx] = sigmoid_f(acc);
}

// ---------- branch-2 + branch-3 finalize, fused (grid 8192) ----------
__global__ void k_bfin(const void* __restrict__ x, const int* __restrict__ dtf,
                       const float* __restrict__ m1, const float* __restrict__ r1,
                       const float* __restrict__ arena,
                       const float* __restrict__ ca, const float* __restrict__ samask,
                       const float* __restrict__ g2,
                       const float* __restrict__ se, const float* __restrict__ g3,
                       ushort_t* __restrict__ cat) {
  bool xf = dtf[0] != 0;
  bool second = blockIdx.x >= 4096;
  int idx = ((int)blockIdx.x & 4095) * 256 + threadIdx.x;
  int hw = idx & 1023, tmp = idx >> 10, c = tmp & 63, bb = tmp >> 6;
  int t = bb * HW_ + hw;
  if (!second) {
    int h = hw >> 5;
    size_t o = ((size_t)bb * DIM_ + 64 + c) * HW_ + hw;
    float v = (ldx(x, o, xf) - m1[t]) * r1[t] * arena[AOFF_N1W + 64 + c] + arena[AOFF_N1B + 64 + c];
    cat[o] = f2us(v * ca[bb*C_ + c] * samask[t] * g2[c*32 + h]);
  } else {
    size_t o = ((size_t)bb * DIM_ + 128 + c) * HW_ + hw;
    float v = (ldx(x, o, xf) - m1[t]) * r1[t] * arena[AOFF_N1W + 128 + c] + arena[AOFF_N1B + 128 + c];
    cat[o] = f2us(v * se[bb*C_ + c] * g3[c*32 + (hw & 31)]);
  }
}

// ---------- branch 4 pointwise via MFMA: [tok,64]@[64,64] + gelu -> t4 [b][c][hw] ----------
__global__ __launch_bounds__(256) void k_b4_mfma(const ushort_t* __restrict__ xn4,
                                                 const ushort_t* __restrict__ wdw,
                                                 const float* __restrict__ arena,
                                                 ushort_t* __restrict__ t4) {
  int w = threadIdx.x >> 6, lane = threadIdx.x & 63;
  int m = lane & 15, quad = lane >> 4;
  int tok0 = blockIdx.x * 64 + w * 16;
  bf16x8 a0 = *(const bf16x8*)(xn4 + (size_t)(tok0 + m) * 64 + quad*8);
  bf16x8 a1 = *(const bf16x8*)(xn4 + (size_t)(tok0 + m) * 64 + 32 + quad*8);
  f32x4 cacc[4];
  #pragma unroll
  for (int nb = 0; nb < 4; ++nb) cacc[nb] = (f32x4){0.f, 0.f, 0.f, 0.f};
  #pragma unroll
  for (int nb = 0; nb < 4; ++nb) {
    bf16x8 b0 = *(const bf16x8*)(wdw + (size_t)(nb*16 + m) * 64 + quad*8);
    bf16x8 b1 = *(const bf16x8*)(wdw + (size_t)(nb*16 + m) * 64 + 32 + quad*8);
    cacc[nb] = __builtin_amdgcn_mfma_f32_16x16x32_bf16(a0, b0, cacc[nb], 0, 0, 0);
    cacc[nb] = __builtin_amdgcn_mfma_f32_16x16x32_bf16(a1, b1, cacc[nb], 0, 0, 0);
  }
  #pragma unroll
  for (int nb = 0; nb < 4; ++nb) {
    int cout = nb*16 + m;
    float bv = arena[AOFF_DWPWB + cout];
    #pragma unroll
    for (int r = 0; r < 4; ++r) {
      int tokg = tok0 + quad*4 + r;
      int bb = tokg >> 10, hw = tokg & 1023;
      t4[((size_t)bb * C_ + cout) * HW_ + hw] = f2us(gelu_f(cacc[nb][r] + bv));
    }
  }
}
__global__ void k_b4_dw(const ushort_t* __restrict__ t4, const float* __restrict__ arena,
                        ushort_t* __restrict__ cat) {
  const float* w = arena + AOFF_DWDW;
  int idx = blockIdx.x * 256 + threadIdx.x;
  int hw = idx & 1023, tmp = idx >> 10, c = tmp & 63, bb = tmp >> 6;
  int yy = hw >> 5, xx = hw & 31;
  const ushort_t* base = t4 + ((size_t)bb * C_ + c) * HW_;
  float acc = arena[AOFF_DWDWB + c];
  #pragma unroll
  for (int ky = 0; ky < 3; ++ky) {
    int ny = yy + ky - 1; if (ny < 0 || ny > 31) continue;
    #pragma unroll
    for (int kx = 0; kx < 3; ++kx) {
      int nx = xx + kx - 1; if (nx < 0 || nx > 31) continue;
      acc += w[c*9 + ky*3 + kx] * us2f(base[ny*32 + nx]);
    }
  }
  cat[((size_t)bb * DIM_ + 192 + c) * HW_ + hw] = f2us(acc);
}

// ---------- LN2: standardize cat IN PLACE, 256 blocks ----------
__global__ __launch_bounds__(256) void k_ln2norm(ushort_t* __restrict__ cat) {
  __shared__ float ps[4][64], ps2[4][64];
  __shared__ float mS[64], rS[64];
  int t = threadIdx.x;
  int pi = t & 63, p = t >> 6;
  int pix = blockIdx.x * 64 + pi;
  int bb = pix >> 10, hw = pix & 1023;
  size_t base = (size_t)bb * (DIM_ * HW_) + hw;
  float v[64];
  float s = 0.f, s2 = 0.f;
  #pragma unroll
  for (int c = 0; c < 64; ++c) {
    v[c] = us2f(cat[base + (size_t)(p * 64 + c) * HW_]);
    s += v[c]; s2 += v[c] * v[c];
  }
  ps[p][pi] = s; ps2[p][pi] = s2;
  __syncthreads();
  if (t < 64) {
    float S = ps[0][t] + ps[1][t] + ps[2][t] + ps[3][t];
    float S2 = ps2[0][t] + ps2[1][t] + ps2[2][t] + ps2[3][t];
    float mean = S * (1.0f / DIM_);
    float var = fmaxf(S2 * (1.0f / DIM_) - mean * mean, 0.f);
    mS[t] = mean;
    rS[t] = rsqrtf(var + 1e-6f);
  }
  __syncthreads();
  float mean = mS[pi], rr = rS[pi];
  #pragma unroll
  for (int c = 0; c < 64; ++c)
    cat[base + (size_t)(p * 64 + c) * HW_] = f2us((v[c] - mean) * rr);
}

// ---------- final depthwise 3x3 on standardized cat (affine folded) + gelu -> z ----------
__global__ void k_final_dw(const ushort_t* __restrict__ cat, const float* __restrict__ arena,
                           ushort_t* __restrict__ z) {
  const float* w = arena + AOFF_LDWDW;
  int idx = blockIdx.x * 256 + threadIdx.x;
  int hw = idx & 1023, tmp = idx >> 10, cc = tmp & 255, bb = tmp >> 8;
  int yy = hw >> 5, xx = hw & 31;
  const ushort_t* base = cat + ((size_t)bb * DIM_ + cc) * HW_;
  float wcc = arena[AOFF_N2W + cc], bcc = arena[AOFF_N2B + cc];
  float sumws = 0.f, sumw = 0.f;
  #pragma unroll
  for (int ky = 0; ky < 3; ++ky) {
    int ny = yy + ky - 1; if (ny < 0 || ny > 31) continue;
    #pragma unroll
    for (int kx = 0; kx < 3; ++kx) {
      int nx = xx + kx - 1; if (nx < 0 || nx > 31) continue;
      float wk = w[cc*9 + ky*3 + kx];
      sumws += wk * us2f(base[ny*32 + nx]);
      sumw  += wk;
    }
  }
  float acc = arena[AOFF_LDWDWB + cc] + wcc * sumws + bcc * sumw;
  z[((size_t)bb * DIM_ + cc) * HW_ + hw] = f2us(gelu_f(acc));
}

// ---------- final pointwise via MFMA ----------
#define ZSTR 264
__global__ __launch_bounds__(256) void k_final_pw_mfma(const ushort_t* __restrict__ z,
                                                       const ushort_t* __restrict__ wpw,
                                                       const float* __restrict__ arena,
                                                       const int* __restrict__ dtf,
                                                       void* __restrict__ out) {
  __shared__ ushort_t zt[64 * ZSTR];
  bool of = dtf[0] != 0;
  int bb = blockIdx.x >> 4, hw0 = (blockIdx.x & 15) * 64;
  int t = threadIdx.x;
  int w = t >> 6, lane = t & 63;
  int m = lane & 15, quad = lane >> 4;
  #pragma unroll
  for (int i = 0; i < 4; ++i) {
    int cp = i * 32 + (t >> 3);
    int c = cp * 2;
    int hw8 = (t & 7) * 8;
    const ushort4* s0 = (const ushort4*)(z + ((size_t)bb * DIM_ + c) * HW_ + hw0 + hw8);
    const ushort4* s1 = (const ushort4*)(z + ((size_t)bb * DIM_ + c + 1) * HW_ + hw0 + hw8);
    ushort4 x0 = s0[0], x1 = s0[1];
    ushort4 y0 = s1[0], y1 = s1[1];
    unsigned int* basep = (unsigned int*)zt;
    basep[(hw8+0)*(ZSTR/2) + cp] = (unsigned int)x0.x | ((unsigned int)y0.x << 16);
    basep[(hw8+1)*(ZSTR/2) + cp] = (unsigned int)x0.y | ((unsigned int)y0.y << 16);
    basep[(hw8+2)*(ZSTR/2) + cp] = (unsigned int)x0.z | ((unsigned int)y0.z << 16);
    basep[(hw8+3)*(ZSTR/2) + cp] = (unsigned int)x0.w | ((unsigned int)y0.w << 16);
    basep[(hw8+4)*(ZSTR/2) + cp] = (unsigned int)x1.x | ((unsigned int)y1.x << 16);
    basep[(hw8+5)*(ZSTR/2) + cp] = (unsigned int)x1.y | ((unsigned int)y1.y << 16);
    basep[(hw8+6)*(ZSTR/2) + cp] = (unsigned int)x1.z | ((unsigned int)y1.z << 16);
    basep[(hw8+7)*(ZSTR/2) + cp] = (unsigned int)x1.w | ((unsigned int)y1.w << 16);
  }
  __syncthreads();
  f32x4 cacc[4][4];
  #pragma unroll
  for (int s = 0; s < 4; ++s)
    #pragma unroll
    for (int nb = 0; nb < 4; ++nb) cacc[s][nb] = (f32x4){0.f, 0.f, 0.f, 0.f};
  for (int kc = 0; kc < 8; ++kc) {
    bf16x8 a[4], b[4];
    #pragma unroll
    for (int s = 0; s < 4; ++s)
      a[s] = *(const bf16x8*)(wpw + (size_t)(w*64 + s*16 + m) * DIM_ + kc*32 + quad*8);
    #pragma unroll
    for (int nb = 0; nb < 4; ++nb)
      b[nb] = *(const bf16x8*)&zt[(nb*16 + m) * ZSTR + kc*32 + quad*8];
    #pragma unroll
    for (int s = 0; s < 4; ++s)
      #pragma unroll
      for (int nb = 0; nb < 4; ++nb)
        cacc[s][nb] = __builtin_amdgcn_mfma_f32_16x16x32_bf16(a[s], b[nb], cacc[s][nb], 0, 0, 0);
  }
  #pragma unroll
  for (int s = 0; s < 4; ++s) {
    #pragma unroll
    for (int r = 0; r < 4; ++r) {
      int d = w*64 + s*16 + quad*4 + r;
      float bv = arena[AOFF_LDWPWB + d];
      #pragma unroll
      for (int nb = 0; nb < 4; ++nb) {
        int hw = hw0 + nb*16 + m;
        float v = cacc[s][nb][r] + bv;
        size_t o = ((size_t)bb * DIM_ + d) * HW_ + hw;
        if (of) ((float*)out)[o] = v; else ((ushort_t*)out)[o] = f2us(v);
      }
    }
  }
}

extern "C" void kernel_launch(void* const* d_in, const int* in_sizes, int n_in,
                              void* d_out, int out_size, void* d_ws, size_t ws_size,
                              hipStream_t stream) {
  const void* x = d_in[0];

  char* wsp = (char*)d_ws; size_t off = 0;
  auto alloc = [&](size_t bytes) -> void* { void* p = wsp + off; off += (bytes + 255) & ~(size_t)255; return p; };

  int*      dtf   = (int*)alloc(sizeof(int));
  float*    arena = (float*)alloc(sizeof(float) * ATOTAL);
  ushort_t* wqkvT = (ushort_t*)alloc(2ull * 1536 * 64);
  ushort_t* woutT = (ushort_t*)alloc(2ull * 64 * 512);
  ushort_t* wpwB  = (ushort_t*)alloc(2ull * DIM_ * DIM_);
  ushort_t* wdwpwB= (ushort_t*)alloc(2ull * C_ * C_);
  ushort_t* x1ln  = (ushort_t*)alloc(2ull * TOK_ * C_);     // 2 MB
  ushort_t* xn4   = (ushort_t*)alloc(2ull * TOK_ * C_);     // 2 MB
  float*    g1    = (float*)alloc(sizeof(float) * C_ * HW_);
  float*    g2    = (float*)alloc(sizeof(float) * C_ * 32);
  float*    g3    = (float*)alloc(sizeof(float) * C_ * 32);
  float*    camean= (float*)alloc(sizeof(float) * B_ * C_);
  float*    camax = (float*)alloc(sizeof(float) * B_ * C_);
  float*    cab   = (float*)alloc(sizeof(float) * B_ * C_);
  float*    sem   = (float*)alloc(sizeof(float) * B_ * C_);
  float*    semx  = (float*)alloc(sizeof(float) * B_ * C_);
  float*    seb   = (float*)alloc(sizeof(float) * B_ * C_);
  float*    spm   = (float*)alloc(sizeof(float) * B_ * HW_);
  float*    spx   = (float*)alloc(sizeof(float) * B_ * HW_);
  float*    sam   = (float*)alloc(sizeof(float) * B_ * HW_);
  float*    m1    = (float*)alloc(sizeof(float) * TOK_);
  float*    r1    = (float*)alloc(sizeof(float) * TOK_);

  const size_t qkv_pb  = 2ull * HEADS_ * 1024 * 64;     // 1 MB per batch (bf16)
  const size_t ao_pb   = 2ull * 1024 * INNER_;          // 1 MB per batch (bf16)
  const size_t z_bytes = 2ull * B_ * DIM_ * HW_;        // 8.39 MB
  size_t remain = (ws_size > off) ? (ws_size - off) : 0;
  int bs = 0;
  for (int cand = B_; cand >= 1; cand >>= 1) {
    size_t need = (size_t)cand * (3 * qkv_pb + ao_pb);
    if (need < z_bytes) need = z_bytes;
    if (need + 65536 <= remain) { bs = cand; break; }
  }
  if (bs == 0) {
    k_probe<<<1, 256, 0, stream>>>((const ushort_t*)x, dtf);
    k_diag<<<16384, 256, 0, stream>>>(d_out, dtf, 100.0f + (float)(ws_size >> 20));
    return;
  }
  const int nsplit = B_ / bs;
  size_t qsz = (size_t)bs * qkv_pb;
  size_t region_bytes = (size_t)bs * (3 * qkv_pb + ao_pb);
  if (region_bytes < z_bytes) region_bytes = z_bytes;
  char* region = (char*)alloc(region_bytes);
  ushort_t* qq   = (ushort_t*)(region);
  ushort_t* kk   = (ushort_t*)(region + qsz);
  ushort_t* vv   = (ushort_t*)(region + 2 * qsz);
  ushort_t* aob  = (ushort_t*)(region + 3 * qsz);
  ushort_t* t4   = (ushort_t*)(region);                  // post-attention
  ushort_t* zbuf = (ushort_t*)(region);                  // final stage
  ushort_t* cat  = (ushort_t*)d_out;

  k_probe<<<1, 256, 0, stream>>>((const ushort_t*)x, dtf);
  k_cvt_all<<<(ATOTAL + 255) / 256, 256, 0, stream>>>(
      d_in[1], d_in[2], d_in[3], d_in[4], d_in[5], d_in[6], d_in[7], d_in[8], d_in[9],
      d_in[10], d_in[11], d_in[12], d_in[13], d_in[14], d_in[15], d_in[16], d_in[17], d_in[18],
      d_in[19], d_in[20], d_in[21], d_in[22], d_in[23], d_in[24], d_in[25], d_in[26], d_in[27],
      d_in[28], d_in[29], d_in[30], d_in[31], d_in[32], d_in[33], d_in[34], d_in[35], d_in[36],
      dtf, arena);
  k_wprep<<<784, 256, 0, stream>>>(arena, wqkvT, woutT, wpwB, wdwpwB);

  k_ln1stats<<<256, 256, 0, stream>>>(x, dtf, m1, r1);
  k_ln_tok<<<256, 256, 0, stream>>>(x, dtf, m1, r1, arena, x1ln, xn4);

  k_gate_xy<<<16, 256, 0, stream>>>(arena, g1);
  k_gate_full<<<2, 256, 0, stream>>>(arena, g2, g3);

  for (int si = 0; si < nsplit; ++si) {
    int tok_base = si * bs * 1024;
    k_qkv_mfma<<<bs * 96, 256, 0, stream>>>(x1ln, wqkvT, qq, kk, vv, tok_base);
    k_flash_mfma<<<bs * HEADS_ * 4, 256, 0, stream>>>(qq, kk, vv, aob);
    k_outproj_mfma<<<bs * 16, 256, 0, stream>>>(aob, woutT, g1, cat, tok_base);
  }

  k_pool2<<<2048, 256, 0, stream>>>(x, dtf, m1, r1, arena, camean, camax, sem, semx);
  k_chmlp<<<32, 64, 0, stream>>>(camean, camax, sem, arena, cab, seb);
  k_spmaps<<<256, 256, 0, stream>>>(x, dtf, m1, r1, arena, cab, spm, spx);
  k_saconv<<<64, 256, 0, stream>>>(spm, spx, arena, sam);
  k_bfin<<<8192, 256, 0, stream>>>(x, dtf, m1, r1, arena, cab, sam, g2, seb, g3, cat);

  k_b4_mfma<<<256, 256, 0, stream>>>(xn4, wdwpwB, arena, t4);
  k_b4_dw<<<4096, 256, 0, stream>>>(t4, arena, cat);

  k_ln2norm<<<256, 256, 0, stream>>>(cat);
  k_final_dw<<<16384, 256, 0, stream>>>(cat, arena, zbuf);
  k_final_pw_mfma<<<256, 256, 0, stream>>>(zbuf, wpwB, arena, dtf, d_out);
}